// Round 3
// baseline (1082.243 us; speedup 1.0000x reference)
//
#include <hip/hip_runtime.h>
#include <cstddef>

#define B0V 8
#define HSV 96
#define WSV 96
#define DMV 192
#define DIV 384
#define MTOT (B0V*HSV*WSV)   // 73728

typedef __attribute__((ext_vector_type(8))) unsigned short ushort8v;

__device__ __forceinline__ float bf2f(unsigned short u) {
    unsigned int i = ((unsigned int)u) << 16;
    float f; __builtin_memcpy(&f, &i, 4); return f;
}
__device__ __forceinline__ unsigned short f2bf(float f) {
    unsigned int i; __builtin_memcpy(&i, &f, 4);
    i += 0x7FFFu + ((i >> 16) & 1);
    return (unsigned short)(i >> 16);
}

// ---------------- K0: Wc(192x192) = W_out(192x384) @ W_in_z(384x192) ----------------
__global__ __launch_bounds__(192) void wc_kernel(
    const float* __restrict__ Wout, const float* __restrict__ Win, float* __restrict__ Wc)
{
    const int o = blockIdx.x;     // 0..191
    const int c = threadIdx.x;    // 0..191
    __shared__ float wrow[384];
    for (int j = threadIdx.x; j < 384; j += 192) wrow[j] = Wout[(size_t)o*384 + j];
    __syncthreads();
    float acc = 0.f;
#pragma unroll 4
    for (int j = 0; j < 384; ++j)
        acc += wrow[j] * Win[(size_t)(384 + j)*192 + c];
    Wc[(size_t)o*192 + c] = acc;
}

// ---------------- K1: xf(bf16) = x(M x 192) @ W_in_f^T(384 x 192) ----------------
__global__ __launch_bounds__(256) void gemm_in_kernel(
    const float* __restrict__ A, const float* __restrict__ Bm,
    unsigned short* __restrict__ xf)
{
    const int m0 = blockIdx.x * 128;
    const int n0 = blockIdx.y * 128;
    __shared__ float As[16][132];
    __shared__ float Bs[16][132];
    const int t  = threadIdx.x;
    const int tx = t & 15, ty = t >> 4;
    float acc[8][8];
#pragma unroll
    for (int i = 0; i < 8; ++i)
#pragma unroll
        for (int j = 0; j < 8; ++j) acc[i][j] = 0.f;

    const int row = t >> 1;
    const int kof = (t & 1) * 8;

    for (int k0 = 0; k0 < 192; k0 += 16) {
        const float* srcA = A  + (size_t)(m0 + row) * 192 + k0 + kof;
        float4 a0 = *(const float4*)(srcA);
        float4 a1 = *(const float4*)(srcA + 4);
        const float* srcB = Bm + (size_t)(n0 + row) * 192 + k0 + kof;
        float4 b0 = *(const float4*)(srcB);
        float4 b1 = *(const float4*)(srcB + 4);
        __syncthreads();
        As[kof+0][row]=a0.x; As[kof+1][row]=a0.y; As[kof+2][row]=a0.z; As[kof+3][row]=a0.w;
        As[kof+4][row]=a1.x; As[kof+5][row]=a1.y; As[kof+6][row]=a1.z; As[kof+7][row]=a1.w;
        Bs[kof+0][row]=b0.x; Bs[kof+1][row]=b0.y; Bs[kof+2][row]=b0.z; Bs[kof+3][row]=b0.w;
        Bs[kof+4][row]=b1.x; Bs[kof+5][row]=b1.y; Bs[kof+6][row]=b1.z; Bs[kof+7][row]=b1.w;
        __syncthreads();
#pragma unroll
        for (int kk = 0; kk < 16; ++kk) {
            float a[8], b[8];
            *(float4*)&a[0] = *(const float4*)&As[kk][ty*8];
            *(float4*)&a[4] = *(const float4*)&As[kk][ty*8+4];
            *(float4*)&b[0] = *(const float4*)&Bs[kk][tx*8];
            *(float4*)&b[4] = *(const float4*)&Bs[kk][tx*8+4];
#pragma unroll
            for (int i = 0; i < 8; ++i)
#pragma unroll
                for (int j = 0; j < 8; ++j) acc[i][j] += a[i]*b[j];
        }
    }
    const int ncol = n0 + tx*8;
#pragma unroll
    for (int i = 0; i < 8; ++i) {
        const int m = m0 + ty*8 + i;
        ushort8v sv;
#pragma unroll
        for (int j = 0; j < 8; ++j) sv[j] = f2bf(acc[i][j]);
        *(ushort8v*)(xf + (size_t)m*DIV + ncol) = sv;
    }
}

// ---------------- K2: depthwise 7x7 conv, pad 3 — register sliding window ----------------
// block = 256 threads: 64 channels x 4 w-positions; each thread: 8 output rows.
// grid = (12*24 tiles, 6 channel-chunks, 8 batches)
__global__ __launch_bounds__(256) void dwconv_kernel(
    const unsigned short* __restrict__ xf, const float* __restrict__ cw,
    const float* __restrict__ cb, unsigned short* __restrict__ xc)
{
    const int tile = blockIdx.x;
    const int th = tile / 24, tw = tile % 24;
    const int h0 = th * 8, w0 = tw * 4;
    const int c0 = blockIdx.y * 64;
    const int b  = blockIdx.z;

    __shared__ float wl[64*49];
    const int t = threadIdx.x;
    for (int idx = t; idx < 64*49; idx += 256)
        wl[idx] = cw[(size_t)c0*49 + idx];
    __syncthreads();

    const int cl = t & 63;           // local channel
    const int cg = c0 + cl;          // global channel
    const int w  = w0 + (t >> 6);    // this thread's output column
    const int wm3 = w - 3;

    float wreg[49];
#pragma unroll
    for (int k = 0; k < 49; ++k) wreg[k] = wl[cl*49 + k];

    float acc[8];
    const float bias = cb[cg];
#pragma unroll
    for (int i = 0; i < 8; ++i) acc[i] = bias;

#pragma unroll
    for (int ih = 0; ih < 14; ++ih) {
        const int row = h0 - 3 + ih;
        const bool rowok = (row >= 0) && (row < HSV);
        float r[7];
#pragma unroll
        for (int j = 0; j < 7; ++j) {
            const int col = wm3 + j;
            float v = 0.f;
            if (rowok && (unsigned)col < (unsigned)WSV)
                v = bf2f(xf[(((size_t)b*HSV + row)*WSV + col)*DIV + cg]);
            r[j] = v;
        }
#pragma unroll
        for (int kh = 0; kh < 7; ++kh) {
            const int oh = ih - kh;
            if (oh >= 0 && oh < 8) {
#pragma unroll
                for (int j = 0; j < 7; ++j)
                    acc[oh] += wreg[kh*7 + j] * r[j];
            }
        }
    }
#pragma unroll
    for (int oh = 0; oh < 8; ++oh)
        xc[(((size_t)b*HSV + h0 + oh)*WSV + w)*DIV + cg] = f2bf(acc[oh]);
}

// ---------------- K3: dilated 3x3 box-sum + LayerNorm ----------------
__global__ __launch_bounds__(384) void boxln_kernel(
    const unsigned short* __restrict__ xc,
    const float* __restrict__ g, const float* __restrict__ bta,
    unsigned short* __restrict__ yln)
{
    const int m = blockIdx.x;            // pixel index
    const int b  = m / (HSV*WSV);
    const int hw = m % (HSV*WSV);
    const int h = hw / WSV, w = hw % WSV;
    const int d = threadIdx.x;           // 0..383
    const int grp = d >> 7;              // d / 128
    const int dd  = grp + 1;             // dilation

    float s = 0.f;
#pragma unroll
    for (int a = -1; a <= 1; ++a)
#pragma unroll
        for (int bb = -1; bb <= 1; ++bb) {
            const int h2 = h + a*dd, w2 = w + bb*dd;
            if (h2 >= 0 && h2 < HSV && w2 >= 0 && w2 < WSV)
                s += bf2f(xc[(((size_t)b*HSV + h2)*WSV + w2)*DIV + d]);
        }

    // LayerNorm over 384 channels
    float v = s, v2 = s*s;
#pragma unroll
    for (int off = 32; off > 0; off >>= 1) {
        v  += __shfl_down(v,  off);
        v2 += __shfl_down(v2, off);
    }
    __shared__ float red[14];
    const int wid = threadIdx.x >> 6, lane = threadIdx.x & 63;
    if (lane == 0) { red[wid] = v; red[6+wid] = v2; }
    __syncthreads();
    if (threadIdx.x == 0) {
        float sv = 0.f, sv2 = 0.f;
        for (int i = 0; i < 6; ++i) { sv += red[i]; sv2 += red[6+i]; }
        const float mu  = sv * (1.f/384.f);
        const float var = sv2 * (1.f/384.f) - mu*mu;
        red[12] = mu;
        red[13] = rsqrtf(var + 1e-5f);
    }
    __syncthreads();
    const float mu = red[12], rstd = red[13];
    yln[(size_t)m*DIV + d] = f2bf((s - mu)*rstd*g[d] + bta[d]);
}

// ---------------- K4: out = yln(bf16, M x 384) @ W_out^T + x @ Wc^T ----------------
__global__ __launch_bounds__(256) void gemm_out_kernel(
    const unsigned short* __restrict__ Yl, const float* __restrict__ Wout,
    const float* __restrict__ x, const float* __restrict__ Wc,
    float* __restrict__ out)
{
    const int m0 = blockIdx.x * 128;
    const int n0 = blockIdx.y * 64;
    __shared__ float As[16][132];
    __shared__ float Bs[16][68];
    const int t  = threadIdx.x;
    const int tx = t & 15, ty = t >> 4;
    float acc[8][4];
#pragma unroll
    for (int i = 0; i < 8; ++i)
#pragma unroll
        for (int j = 0; j < 4; ++j) acc[i][j] = 0.f;

    const int rowA = t >> 1; const int kofA = (t & 1) * 8;
    const int rowB = t >> 2; const int kofB = (t & 3) * 4;

    // phase 1: K=384 over yln (bf16) x W_out (f32)
    for (int k0 = 0; k0 < 384; k0 += 16) {
        ushort8v av = *(const ushort8v*)(Yl + (size_t)(m0 + rowA) * DIV + k0 + kofA);
        float4 b0 = *(const float4*)(Wout + (size_t)(n0 + rowB) * DIV + k0 + kofB);
        __syncthreads();
#pragma unroll
        for (int j = 0; j < 8; ++j) As[kofA+j][rowA] = bf2f(av[j]);
        Bs[kofB+0][rowB]=b0.x; Bs[kofB+1][rowB]=b0.y; Bs[kofB+2][rowB]=b0.z; Bs[kofB+3][rowB]=b0.w;
        __syncthreads();
#pragma unroll
        for (int kk = 0; kk < 16; ++kk) {
            float a[8], b[4];
            *(float4*)&a[0] = *(const float4*)&As[kk][ty*8];
            *(float4*)&a[4] = *(const float4*)&As[kk][ty*8+4];
            *(float4*)&b[0] = *(const float4*)&Bs[kk][tx*4];
#pragma unroll
            for (int i = 0; i < 8; ++i)
#pragma unroll
                for (int j = 0; j < 4; ++j) acc[i][j] += a[i]*b[j];
        }
    }
    // phase 2: K=192 over x (f32) x Wc (f32)
    for (int k0 = 0; k0 < 192; k0 += 16) {
        const float* srcA = x + (size_t)(m0 + rowA) * 192 + k0 + kofA;
        float4 a0 = *(const float4*)(srcA);
        float4 a1 = *(const float4*)(srcA + 4);
        float4 b0 = *(const float4*)(Wc + (size_t)(n0 + rowB) * 192 + k0 + kofB);
        __syncthreads();
        As[kofA+0][rowA]=a0.x; As[kofA+1][rowA]=a0.y; As[kofA+2][rowA]=a0.z; As[kofA+3][rowA]=a0.w;
        As[kofA+4][rowA]=a1.x; As[kofA+5][rowA]=a1.y; As[kofA+6][rowA]=a1.z; As[kofA+7][rowA]=a1.w;
        Bs[kofB+0][rowB]=b0.x; Bs[kofB+1][rowB]=b0.y; Bs[kofB+2][rowB]=b0.z; Bs[kofB+3][rowB]=b0.w;
        __syncthreads();
#pragma unroll
        for (int kk = 0; kk < 16; ++kk) {
            float a[8], b[4];
            *(float4*)&a[0] = *(const float4*)&As[kk][ty*8];
            *(float4*)&a[4] = *(const float4*)&As[kk][ty*8+4];
            *(float4*)&b[0] = *(const float4*)&Bs[kk][tx*4];
#pragma unroll
            for (int i = 0; i < 8; ++i)
#pragma unroll
                for (int j = 0; j < 4; ++j) acc[i][j] += a[i]*b[j];
        }
    }
    const int ncol = n0 + tx*4;
#pragma unroll
    for (int i = 0; i < 8; ++i) {
        const int m = m0 + ty*8 + i;
        float4 s0 = make_float4(acc[i][0],acc[i][1],acc[i][2],acc[i][3]);
        *(float4*)(out + (size_t)m*DMV + ncol) = s0;
    }
}

extern "C" void kernel_launch(void* const* d_in, const int* in_sizes, int n_in,
                              void* d_out, int out_size, void* d_ws, size_t ws_size,
                              hipStream_t stream)
{
    const float* x      = (const float*)d_in[0];
    const float* W_in   = (const float*)d_in[1];
    const float* conv_w = (const float*)d_in[2];
    const float* conv_b = (const float*)d_in[3];
    const float* ln_g   = (const float*)d_in[11];
    const float* ln_b   = (const float*)d_in[12];
    const float* W_out  = (const float*)d_in[13];
    float* out = (float*)d_out;

    // workspace layout (total ~108.2 MiB):
    //   Wc  : 192*192 f32
    //   xf  : M*384 bf16  (reused for yln)
    //   xc  : M*384 bf16
    float* Wc = (float*)d_ws;
    unsigned short* xf = (unsigned short*)((char*)d_ws + 192*192*sizeof(float));
    unsigned short* xc = xf + (size_t)MTOT * DIV;

    wc_kernel      <<<dim3(192),           192, 0, stream>>>(W_out, W_in, Wc);
    gemm_in_kernel <<<dim3(MTOT/128, 3),   256, 0, stream>>>(x, W_in, xf);
    dwconv_kernel  <<<dim3(288, 6, B0V),   256, 0, stream>>>(xf, conv_w, conv_b, xc);
    boxln_kernel   <<<dim3(MTOT),          384, 0, stream>>>(xc, ln_g, ln_b, xf);
    gemm_out_kernel<<<dim3(MTOT/128, 3),   256, 0, stream>>>(xf, W_out, x, Wc, out);
}

// Round 4
// 447.195 us; speedup vs baseline: 2.4201x; 2.4201x over previous
//
#include <hip/hip_runtime.h>
#include <cstddef>

#define B0V 8
#define HSV 96
#define WSV 96
#define DMV 192
#define DIV 384
#define MTOT (B0V*HSV*WSV)   // 73728

typedef __attribute__((ext_vector_type(8))) unsigned short ushort8v;
typedef __attribute__((ext_vector_type(8))) short short8v;
typedef __attribute__((ext_vector_type(4))) float f32x4;

__device__ __forceinline__ float bf2f(unsigned short u) {
    unsigned int i = ((unsigned int)u) << 16;
    float f; __builtin_memcpy(&f, &i, 4); return f;
}
__device__ __forceinline__ unsigned short f2bf(float f) {
    unsigned int i; __builtin_memcpy(&i, &f, 4);
    i += 0x7FFFu + ((i >> 16) & 1);
    return (unsigned short)(i >> 16);
}

// ---- LDS staging helpers: tile stored [ROWS][64] bf16, 16B chunks XOR-swizzled by (row&7) ----
template<int ROWS>
__device__ __forceinline__ void stageF32(const float* __restrict__ src, int ld,
                                         unsigned short* lds, int t) {
#pragma unroll
    for (int i = 0; i < ROWS*8/256; ++i) {
        const int cid = t + i*256;
        const int r = cid >> 3, cb = cid & 7;
        const float* p = src + (size_t)r*ld + cb*8;
        float4 f0 = *(const float4*)p;
        float4 f1 = *(const float4*)(p+4);
        ushort8v sv;
        sv[0]=f2bf(f0.x); sv[1]=f2bf(f0.y); sv[2]=f2bf(f0.z); sv[3]=f2bf(f0.w);
        sv[4]=f2bf(f1.x); sv[5]=f2bf(f1.y); sv[6]=f2bf(f1.z); sv[7]=f2bf(f1.w);
        *(ushort8v*)((char*)lds + r*128 + ((cb ^ (r&7))<<4)) = sv;
    }
}
template<int ROWS>
__device__ __forceinline__ void stageBF16(const unsigned short* __restrict__ src, int ld,
                                          unsigned short* lds, int t) {
#pragma unroll
    for (int i = 0; i < ROWS*8/256; ++i) {
        const int cid = t + i*256;
        const int r = cid >> 3, cb = cid & 7;
        ushort8v sv = *(const ushort8v*)(src + (size_t)r*ld + cb*8);
        *(ushort8v*)((char*)lds + r*128 + ((cb ^ (r&7))<<4)) = sv;
    }
}
__device__ __forceinline__ short8v fragRead(const unsigned short* lds, int row, int kchunk) {
    return *(const short8v*)((const char*)lds + row*128 + ((kchunk ^ (row&7))<<4));
}

// ---------------- K0: Wc(192x192) = W_out(192x384) @ W_in_z(384x192) ----------------
__global__ __launch_bounds__(192) void wc_kernel(
    const float* __restrict__ Wout, const float* __restrict__ Win, float* __restrict__ Wc)
{
    const int o = blockIdx.x;
    const int c = threadIdx.x;
    __shared__ float wrow[384];
    for (int j = threadIdx.x; j < 384; j += 192) wrow[j] = Wout[(size_t)o*384 + j];
    __syncthreads();
    float acc = 0.f;
#pragma unroll 4
    for (int j = 0; j < 384; ++j)
        acc += wrow[j] * Win[(size_t)(384 + j)*192 + c];
    Wc[(size_t)o*192 + c] = acc;
}

// ---------------- K1: xf(bf16, Mx384) = x(Mx192) @ W_in_f^T  (MFMA) ----------------
__global__ __launch_bounds__(256) void gemm_in_mfma(
    const float* __restrict__ x, const float* __restrict__ W,
    unsigned short* __restrict__ xf)
{
    __shared__ unsigned short As[128*64];
    __shared__ unsigned short Bs[128*64];
    const int t = threadIdx.x;
    const int m0 = blockIdx.x * 128, n0 = blockIdx.y * 128;
    const int wid = t >> 6, lane = t & 63;
    const int wm = wid >> 1, wn = wid & 1;
    const int li = lane & 15, lg = lane >> 4;

    f32x4 acc[4][4];
#pragma unroll
    for (int i = 0; i < 4; ++i)
#pragma unroll
        for (int j = 0; j < 4; ++j) acc[i][j] = (f32x4){0.f,0.f,0.f,0.f};

    for (int kb = 0; kb < 3; ++kb) {
        stageF32<128>(x + (size_t)m0*DMV + kb*64, DMV, As, t);
        stageF32<128>(W + (size_t)n0*DMV + kb*64, DMV, Bs, t);
        __syncthreads();
#pragma unroll
        for (int ks = 0; ks < 2; ++ks) {
            short8v a[4], b[4];
#pragma unroll
            for (int mf = 0; mf < 4; ++mf) a[mf] = fragRead(As, wm*64 + mf*16 + li, ks*4 + lg);
#pragma unroll
            for (int nf = 0; nf < 4; ++nf) b[nf] = fragRead(Bs, wn*64 + nf*16 + li, ks*4 + lg);
#pragma unroll
            for (int mf = 0; mf < 4; ++mf)
#pragma unroll
                for (int nf = 0; nf < 4; ++nf)
                    acc[mf][nf] = __builtin_amdgcn_mfma_f32_16x16x32_bf16(a[mf], b[nf], acc[mf][nf], 0, 0, 0);
        }
        __syncthreads();
    }
#pragma unroll
    for (int mf = 0; mf < 4; ++mf)
#pragma unroll
        for (int nf = 0; nf < 4; ++nf)
#pragma unroll
            for (int i = 0; i < 4; ++i) {
                const int row = m0 + wm*64 + mf*16 + lg*4 + i;
                const int col = n0 + wn*64 + nf*16 + li;
                xf[(size_t)row*DIV + col] = f2bf(acc[mf][nf][i]);
            }
}

// ---------------- K2: depthwise 7x7 conv — LDS patch + register sliding window ----------------
// tile 8h x 16w x 64c; 256 thr = 64c x 4 wq; thread: 4 cols x 8 rows
__global__ __launch_bounds__(256) void dwconv_kernel(
    const unsigned short* __restrict__ xf, const float* __restrict__ cw,
    const float* __restrict__ cb, unsigned short* __restrict__ xc)
{
    const int tile = blockIdx.x;            // 72 = 12h x 6w
    const int th = tile / 6, tw = tile % 6;
    const int h0 = th*8, w0 = tw*16;
    const int c0 = blockIdx.y*64, b = blockIdx.z;

    __shared__ unsigned short patch[14*22*64];
    __shared__ float wl[64*49];
    const int t = threadIdx.x;
    for (int i = t; i < 64*49; i += 256) wl[i] = cw[(size_t)c0*49 + i];
    for (int idx = t; idx < 308*8; idx += 256) {
        const int sp = idx >> 3, c8 = idx & 7;
        const int ih = sp / 22, iw = sp % 22;
        const int gh = h0 - 3 + ih, gw = w0 - 3 + iw;
        ushort8v v;
#pragma unroll
        for (int j = 0; j < 8; ++j) v[j] = 0;
        if ((unsigned)gh < (unsigned)HSV && (unsigned)gw < (unsigned)WSV)
            v = *(const ushort8v*)(xf + (((size_t)b*HSV + gh)*WSV + gw)*DIV + c0 + c8*8);
        *(ushort8v*)(patch + sp*64 + c8*8) = v;
    }
    __syncthreads();

    const int c = t & 63, wq = t >> 6;
    float wreg[49];
#pragma unroll
    for (int k = 0; k < 49; ++k) wreg[k] = wl[c*49 + k];

    float acc[8][4];
    const float bias = cb[c0 + c];
#pragma unroll
    for (int i = 0; i < 8; ++i)
#pragma unroll
        for (int j = 0; j < 4; ++j) acc[i][j] = bias;

#pragma unroll
    for (int ih = 0; ih < 14; ++ih) {
        float r[10];
#pragma unroll
        for (int j = 0; j < 10; ++j)
            r[j] = bf2f(patch[(ih*22 + wq*4 + j)*64 + c]);
#pragma unroll
        for (int kh = 0; kh < 7; ++kh) {
            const int oh = ih - kh;
            if (oh >= 0 && oh < 8) {
#pragma unroll
                for (int kw = 0; kw < 7; ++kw)
#pragma unroll
                    for (int j = 0; j < 4; ++j)
                        acc[oh][j] += wreg[kh*7 + kw] * r[j + kw];
            }
        }
    }
#pragma unroll
    for (int oh = 0; oh < 8; ++oh)
#pragma unroll
        for (int j = 0; j < 4; ++j)
            xc[(((size_t)b*HSV + h0+oh)*WSV + (w0 + wq*4 + j))*DIV + c0 + c] = f2bf(acc[oh][j]);
}

// ---------------- K3: dilated 3x3 box-sum + LayerNorm ----------------
__global__ __launch_bounds__(384) void boxln_kernel(
    const unsigned short* __restrict__ xc,
    const float* __restrict__ g, const float* __restrict__ bta,
    unsigned short* __restrict__ yln)
{
    const int m = blockIdx.x;
    const int b  = m / (HSV*WSV);
    const int hw = m % (HSV*WSV);
    const int h = hw / WSV, w = hw % WSV;
    const int d = threadIdx.x;
    const int dd = (d >> 7) + 1;

    float s = 0.f;
#pragma unroll
    for (int a = -1; a <= 1; ++a)
#pragma unroll
        for (int bb = -1; bb <= 1; ++bb) {
            const int h2 = h + a*dd, w2 = w + bb*dd;
            if (h2 >= 0 && h2 < HSV && w2 >= 0 && w2 < WSV)
                s += bf2f(xc[(((size_t)b*HSV + h2)*WSV + w2)*DIV + d]);
        }

    float v = s, v2 = s*s;
#pragma unroll
    for (int off = 32; off > 0; off >>= 1) {
        v  += __shfl_down(v,  off);
        v2 += __shfl_down(v2, off);
    }
    __shared__ float red[14];
    const int wid = threadIdx.x >> 6, lane = threadIdx.x & 63;
    if (lane == 0) { red[wid] = v; red[6+wid] = v2; }
    __syncthreads();
    if (threadIdx.x == 0) {
        float sv = 0.f, sv2 = 0.f;
        for (int i = 0; i < 6; ++i) { sv += red[i]; sv2 += red[6+i]; }
        const float mu  = sv * (1.f/384.f);
        const float var = sv2 * (1.f/384.f) - mu*mu;
        red[12] = mu;
        red[13] = rsqrtf(var + 1e-5f);
    }
    __syncthreads();
    const float mu = red[12], rstd = red[13];
    yln[(size_t)m*DIV + d] = f2bf((s - mu)*rstd*g[d] + bta[d]);
}

// ---------------- K4: out(f32, Mx192) = yln @ W_out^T + x @ Wc^T  (MFMA) ----------------
__global__ __launch_bounds__(256) void gemm_out_mfma(
    const unsigned short* __restrict__ Yl, const float* __restrict__ Wout,
    const float* __restrict__ x, const float* __restrict__ Wc,
    float* __restrict__ out)
{
    __shared__ unsigned short As[128*64];
    __shared__ unsigned short Bs[64*64];
    const int t = threadIdx.x;
    const int m0 = blockIdx.x * 128, n0 = blockIdx.y * 64;
    const int wid = t >> 6, lane = t & 63;
    const int wm = wid >> 1, wn = wid & 1;
    const int li = lane & 15, lg = lane >> 4;

    f32x4 acc[4][2];
#pragma unroll
    for (int i = 0; i < 4; ++i)
#pragma unroll
        for (int j = 0; j < 2; ++j) acc[i][j] = (f32x4){0.f,0.f,0.f,0.f};

    // phase 1: yln (bf16) @ W_out^T, K=384
    for (int kb = 0; kb < 6; ++kb) {
        stageBF16<128>(Yl + (size_t)m0*DIV + kb*64, DIV, As, t);
        stageF32<64> (Wout + (size_t)n0*DIV + kb*64, DIV, Bs, t);
        __syncthreads();
#pragma unroll
        for (int ks = 0; ks < 2; ++ks) {
            short8v a[4], b[2];
#pragma unroll
            for (int mf = 0; mf < 4; ++mf) a[mf] = fragRead(As, wm*64 + mf*16 + li, ks*4 + lg);
#pragma unroll
            for (int nf = 0; nf < 2; ++nf) b[nf] = fragRead(Bs, wn*32 + nf*16 + li, ks*4 + lg);
#pragma unroll
            for (int mf = 0; mf < 4; ++mf)
#pragma unroll
                for (int nf = 0; nf < 2; ++nf)
                    acc[mf][nf] = __builtin_amdgcn_mfma_f32_16x16x32_bf16(a[mf], b[nf], acc[mf][nf], 0, 0, 0);
        }
        __syncthreads();
    }
    // phase 2: x (f32->bf16) @ Wc^T, K=192
    for (int kb = 0; kb < 3; ++kb) {
        stageF32<128>(x  + (size_t)m0*DMV + kb*64, DMV, As, t);
        stageF32<64> (Wc + (size_t)n0*DMV + kb*64, DMV, Bs, t);
        __syncthreads();
#pragma unroll
        for (int ks = 0; ks < 2; ++ks) {
            short8v a[4], b[2];
#pragma unroll
            for (int mf = 0; mf < 4; ++mf) a[mf] = fragRead(As, wm*64 + mf*16 + li, ks*4 + lg);
#pragma unroll
            for (int nf = 0; nf < 2; ++nf) b[nf] = fragRead(Bs, wn*32 + nf*16 + li, ks*4 + lg);
#pragma unroll
            for (int mf = 0; mf < 4; ++mf)
#pragma unroll
                for (int nf = 0; nf < 2; ++nf)
                    acc[mf][nf] = __builtin_amdgcn_mfma_f32_16x16x32_bf16(a[mf], b[nf], acc[mf][nf], 0, 0, 0);
        }
        __syncthreads();
    }
#pragma unroll
    for (int mf = 0; mf < 4; ++mf)
#pragma unroll
        for (int nf = 0; nf < 2; ++nf)
#pragma unroll
            for (int i = 0; i < 4; ++i) {
                const int row = m0 + wm*64 + mf*16 + lg*4 + i;
                const int col = n0 + wn*32 + nf*16 + li;
                out[(size_t)row*DMV + col] = acc[mf][nf][i];
            }
}

extern "C" void kernel_launch(void* const* d_in, const int* in_sizes, int n_in,
                              void* d_out, int out_size, void* d_ws, size_t ws_size,
                              hipStream_t stream)
{
    const float* x      = (const float*)d_in[0];
    const float* W_in   = (const float*)d_in[1];
    const float* conv_w = (const float*)d_in[2];
    const float* conv_b = (const float*)d_in[3];
    const float* ln_g   = (const float*)d_in[11];
    const float* ln_b   = (const float*)d_in[12];
    const float* W_out  = (const float*)d_in[13];
    float* out = (float*)d_out;

    // ws layout (same footprint as known-good round 3): Wc f32 | xf bf16 | xc bf16
    float* Wc = (float*)d_ws;
    unsigned short* xf = (unsigned short*)((char*)d_ws + 192*192*sizeof(float));
    unsigned short* xc = xf + (size_t)MTOT * DIV;

    wc_kernel    <<<dim3(192),          192, 0, stream>>>(W_out, W_in, Wc);
    gemm_in_mfma <<<dim3(MTOT/128, 3),  256, 0, stream>>>(x, W_in, xf);
    dwconv_kernel<<<dim3(72, 6, B0V),   256, 0, stream>>>(xf, conv_w, conv_b, xc);
    boxln_kernel <<<dim3(MTOT),         384, 0, stream>>>(xc, ln_g, ln_b, xf);
    gemm_out_mfma<<<dim3(MTOT/128, 3),  256, 0, stream>>>(xf, W_out, x, Wc, out);
}

// Round 5
// 246.321 us; speedup vs baseline: 4.3936x; 1.8155x over previous
//
#include <hip/hip_runtime.h>
#include <cstddef>

#define B0V 8
#define HSV 96
#define WSV 96
#define DMV 192
#define DIV 384
#define MTOT (B0V*HSV*WSV)   // 73728

typedef __attribute__((ext_vector_type(8))) unsigned short ushort8v;
typedef __attribute__((ext_vector_type(8))) short short8v;
typedef __attribute__((ext_vector_type(4))) float f32x4;

__device__ __forceinline__ float bf2f(unsigned short u) {
    unsigned int i = ((unsigned int)u) << 16;
    float f; __builtin_memcpy(&f, &i, 4); return f;
}
__device__ __forceinline__ unsigned short f2bf(float f) {
    unsigned int i; __builtin_memcpy(&i, &f, 4);
    i += 0x7FFFu + ((i >> 16) & 1);
    return (unsigned short)(i >> 16);
}

// ---- LDS staging helpers: tile stored [ROWS][64] bf16, 16B chunks XOR-swizzled by (row&7) ----
template<int ROWS>
__device__ __forceinline__ void stageF32(const float* __restrict__ src, int ld,
                                         unsigned short* lds, int t) {
#pragma unroll
    for (int i = 0; i < ROWS*8/256; ++i) {
        const int cid = t + i*256;
        const int r = cid >> 3, cb = cid & 7;
        const float* p = src + (size_t)r*ld + cb*8;
        float4 f0 = *(const float4*)p;
        float4 f1 = *(const float4*)(p+4);
        ushort8v sv;
        sv[0]=f2bf(f0.x); sv[1]=f2bf(f0.y); sv[2]=f2bf(f0.z); sv[3]=f2bf(f0.w);
        sv[4]=f2bf(f1.x); sv[5]=f2bf(f1.y); sv[6]=f2bf(f1.z); sv[7]=f2bf(f1.w);
        *(ushort8v*)((char*)lds + r*128 + ((cb ^ (r&7))<<4)) = sv;
    }
}
template<int ROWS>
__device__ __forceinline__ void stageBF16(const unsigned short* __restrict__ src, int ld,
                                          unsigned short* lds, int t) {
#pragma unroll
    for (int i = 0; i < ROWS*8/256; ++i) {
        const int cid = t + i*256;
        const int r = cid >> 3, cb = cid & 7;
        ushort8v sv = *(const ushort8v*)(src + (size_t)r*ld + cb*8);
        *(ushort8v*)((char*)lds + r*128 + ((cb ^ (r&7))<<4)) = sv;
    }
}
__device__ __forceinline__ short8v fragRead(const unsigned short* lds, int row, int kchunk) {
    return *(const short8v*)((const char*)lds + row*128 + ((kchunk ^ (row&7))<<4));
}

// ---------------- K0: Wc(192x192) = W_out(192x384) @ W_in_z(384x192) ----------------
__global__ __launch_bounds__(192) void wc_kernel(
    const float* __restrict__ Wout, const float* __restrict__ Win, float* __restrict__ Wc)
{
    const int o = blockIdx.x;
    const int c = threadIdx.x;
    __shared__ float wrow[384];
    for (int j = threadIdx.x; j < 384; j += 192) wrow[j] = Wout[(size_t)o*384 + j];
    __syncthreads();
    float acc = 0.f;
#pragma unroll 4
    for (int j = 0; j < 384; ++j)
        acc += wrow[j] * Win[(size_t)(384 + j)*192 + c];
    Wc[(size_t)o*192 + c] = acc;
}

// ---------------- K1: xf(bf16, Mx384) = x(Mx192) @ W_in_f^T  (MFMA) ----------------
__global__ __launch_bounds__(256) void gemm_in_mfma(
    const float* __restrict__ x, const float* __restrict__ W,
    unsigned short* __restrict__ xf)
{
    __shared__ unsigned short As[128*64];
    __shared__ unsigned short Bs[128*64];
    const int t = threadIdx.x;
    const int m0 = blockIdx.x * 128, n0 = blockIdx.y * 128;
    const int wid = t >> 6, lane = t & 63;
    const int wm = wid >> 1, wn = wid & 1;
    const int li = lane & 15, lg = lane >> 4;

    f32x4 acc[4][4];
#pragma unroll
    for (int i = 0; i < 4; ++i)
#pragma unroll
        for (int j = 0; j < 4; ++j) acc[i][j] = (f32x4){0.f,0.f,0.f,0.f};

    for (int kb = 0; kb < 3; ++kb) {
        stageF32<128>(x + (size_t)m0*DMV + kb*64, DMV, As, t);
        stageF32<128>(W + (size_t)n0*DMV + kb*64, DMV, Bs, t);
        __syncthreads();
#pragma unroll
        for (int ks = 0; ks < 2; ++ks) {
            short8v a[4], b[4];
#pragma unroll
            for (int mf = 0; mf < 4; ++mf) a[mf] = fragRead(As, wm*64 + mf*16 + li, ks*4 + lg);
#pragma unroll
            for (int nf = 0; nf < 4; ++nf) b[nf] = fragRead(Bs, wn*64 + nf*16 + li, ks*4 + lg);
#pragma unroll
            for (int mf = 0; mf < 4; ++mf)
#pragma unroll
                for (int nf = 0; nf < 4; ++nf)
                    acc[mf][nf] = __builtin_amdgcn_mfma_f32_16x16x32_bf16(a[mf], b[nf], acc[mf][nf], 0, 0, 0);
        }
        __syncthreads();
    }
#pragma unroll
    for (int mf = 0; mf < 4; ++mf)
#pragma unroll
        for (int nf = 0; nf < 4; ++nf)
#pragma unroll
            for (int i = 0; i < 4; ++i) {
                const int row = m0 + wm*64 + mf*16 + lg*4 + i;
                const int col = n0 + wn*64 + nf*16 + li;
                xf[(size_t)row*DIV + col] = f2bf(acc[mf][nf][i]);
            }
}

// ---------------- K2: depthwise 7x7 conv — LDS patch + register sliding window ----------------
__global__ __launch_bounds__(256) void dwconv_kernel(
    const unsigned short* __restrict__ xf, const float* __restrict__ cw,
    const float* __restrict__ cb, unsigned short* __restrict__ xc)
{
    const int tile = blockIdx.x;            // 72 = 12h x 6w
    const int th = tile / 6, tw = tile % 6;
    const int h0 = th*8, w0 = tw*16;
    const int c0 = blockIdx.y*64, b = blockIdx.z;

    __shared__ unsigned short patch[14*22*64];
    __shared__ float wl[64*49];
    const int t = threadIdx.x;
    for (int i = t; i < 64*49; i += 256) wl[i] = cw[(size_t)c0*49 + i];
    for (int idx = t; idx < 308*8; idx += 256) {
        const int sp = idx >> 3, c8 = idx & 7;
        const int ih = sp / 22, iw = sp % 22;
        const int gh = h0 - 3 + ih, gw = w0 - 3 + iw;
        ushort8v v;
#pragma unroll
        for (int j = 0; j < 8; ++j) v[j] = 0;
        if ((unsigned)gh < (unsigned)HSV && (unsigned)gw < (unsigned)WSV)
            v = *(const ushort8v*)(xf + (((size_t)b*HSV + gh)*WSV + gw)*DIV + c0 + c8*8);
        *(ushort8v*)(patch + sp*64 + c8*8) = v;
    }
    __syncthreads();

    const int c = t & 63, wq = t >> 6;
    float wreg[49];
#pragma unroll
    for (int k = 0; k < 49; ++k) wreg[k] = wl[c*49 + k];

    float acc[8][4];
    const float bias = cb[c0 + c];
#pragma unroll
    for (int i = 0; i < 8; ++i)
#pragma unroll
        for (int j = 0; j < 4; ++j) acc[i][j] = bias;

#pragma unroll
    for (int ih = 0; ih < 14; ++ih) {
        float r[10];
#pragma unroll
        for (int j = 0; j < 10; ++j)
            r[j] = bf2f(patch[(ih*22 + wq*4 + j)*64 + c]);
#pragma unroll
        for (int kh = 0; kh < 7; ++kh) {
            const int oh = ih - kh;
            if (oh >= 0 && oh < 8) {
#pragma unroll
                for (int kw = 0; kw < 7; ++kw)
#pragma unroll
                    for (int j = 0; j < 4; ++j)
                        acc[oh][j] += wreg[kh*7 + kw] * r[j + kw];
            }
        }
    }
#pragma unroll
    for (int oh = 0; oh < 8; ++oh)
#pragma unroll
        for (int j = 0; j < 4; ++j)
            xc[(((size_t)b*HSV + h0+oh)*WSV + (w0 + wq*4 + j))*DIV + c0 + c] = f2bf(acc[oh][j]);
}

// ---------------- K3: dilated 3x3 box-sum + LayerNorm — wave per pixel ----------------
// 256 thr = 4 waves = 4 pixels; lane l<48 owns channels [8l, 8l+8) via ushort8 loads.
__global__ __launch_bounds__(256) void boxln_kernel(
    const unsigned short* __restrict__ xc,
    const float* __restrict__ g, const float* __restrict__ bta,
    unsigned short* __restrict__ yln)
{
    const int wid  = threadIdx.x >> 6;
    const int lane = threadIdx.x & 63;
    const int m = blockIdx.x * 4 + wid;          // pixel index
    const int b  = m / (HSV*WSV);
    const int hw = m % (HSV*WSV);
    const int h = hw / WSV, w = hw % WSV;

    const bool act = lane < 48;
    const int ch = lane * 8;                     // 0..376
    const int dd = (ch >> 7) + 1;                // dilation 1/2/3 (uniform per lane)

    float s[8];
#pragma unroll
    for (int j = 0; j < 8; ++j) s[j] = 0.f;

#pragma unroll
    for (int a = -1; a <= 1; ++a)
#pragma unroll
        for (int bb = -1; bb <= 1; ++bb) {
            const int h2 = h + a*dd, w2 = w + bb*dd;
            if (act && (unsigned)h2 < (unsigned)HSV && (unsigned)w2 < (unsigned)WSV) {
                ushort8v v = *(const ushort8v*)(xc + (((size_t)b*HSV + h2)*WSV + w2)*DIV + ch);
#pragma unroll
                for (int j = 0; j < 8; ++j) s[j] += bf2f(v[j]);
            }
        }

    float ps = 0.f, ps2 = 0.f;
#pragma unroll
    for (int j = 0; j < 8; ++j) { ps += s[j]; ps2 += s[j]*s[j]; }
#pragma unroll
    for (int off = 32; off > 0; off >>= 1) {
        ps  += __shfl_xor(ps,  off);
        ps2 += __shfl_xor(ps2, off);
    }
    const float mu   = ps * (1.f/384.f);
    const float var  = ps2 * (1.f/384.f) - mu*mu;
    const float rstd = rsqrtf(var + 1e-5f);

    if (act) {
        float4 g0 = *(const float4*)(g + ch);
        float4 g1 = *(const float4*)(g + ch + 4);
        float4 b0 = *(const float4*)(bta + ch);
        float4 b1 = *(const float4*)(bta + ch + 4);
        float gv[8] = {g0.x,g0.y,g0.z,g0.w,g1.x,g1.y,g1.z,g1.w};
        float bv[8] = {b0.x,b0.y,b0.z,b0.w,b1.x,b1.y,b1.z,b1.w};
        ushort8v o;
#pragma unroll
        for (int j = 0; j < 8; ++j)
            o[j] = f2bf((s[j] - mu)*rstd*gv[j] + bv[j]);
        *(ushort8v*)(yln + (size_t)m*DIV + ch) = o;
    }
}

// ---------------- K4: out(f32, Mx192) = yln @ W_out^T + x @ Wc^T  (MFMA) ----------------
__global__ __launch_bounds__(256) void gemm_out_mfma(
    const unsigned short* __restrict__ Yl, const float* __restrict__ Wout,
    const float* __restrict__ x, const float* __restrict__ Wc,
    float* __restrict__ out)
{
    __shared__ unsigned short As[128*64];
    __shared__ unsigned short Bs[64*64];
    const int t = threadIdx.x;
    const int m0 = blockIdx.x * 128, n0 = blockIdx.y * 64;
    const int wid = t >> 6, lane = t & 63;
    const int wm = wid >> 1, wn = wid & 1;
    const int li = lane & 15, lg = lane >> 4;

    f32x4 acc[4][2];
#pragma unroll
    for (int i = 0; i < 4; ++i)
#pragma unroll
        for (int j = 0; j < 2; ++j) acc[i][j] = (f32x4){0.f,0.f,0.f,0.f};

    // phase 1: yln (bf16) @ W_out^T, K=384
    for (int kb = 0; kb < 6; ++kb) {
        stageBF16<128>(Yl + (size_t)m0*DIV + kb*64, DIV, As, t);
        stageF32<64> (Wout + (size_t)n0*DIV + kb*64, DIV, Bs, t);
        __syncthreads();
#pragma unroll
        for (int ks = 0; ks < 2; ++ks) {
            short8v a[4], b[2];
#pragma unroll
            for (int mf = 0; mf < 4; ++mf) a[mf] = fragRead(As, wm*64 + mf*16 + li, ks*4 + lg);
#pragma unroll
            for (int nf = 0; nf < 2; ++nf) b[nf] = fragRead(Bs, wn*32 + nf*16 + li, ks*4 + lg);
#pragma unroll
            for (int mf = 0; mf < 4; ++mf)
#pragma unroll
                for (int nf = 0; nf < 2; ++nf)
                    acc[mf][nf] = __builtin_amdgcn_mfma_f32_16x16x32_bf16(a[mf], b[nf], acc[mf][nf], 0, 0, 0);
        }
        __syncthreads();
    }
    // phase 2: x (f32->bf16) @ Wc^T, K=192
    for (int kb = 0; kb < 3; ++kb) {
        stageF32<128>(x  + (size_t)m0*DMV + kb*64, DMV, As, t);
        stageF32<64> (Wc + (size_t)n0*DMV + kb*64, DMV, Bs, t);
        __syncthreads();
#pragma unroll
        for (int ks = 0; ks < 2; ++ks) {
            short8v a[4], b[2];
#pragma unroll
            for (int mf = 0; mf < 4; ++mf) a[mf] = fragRead(As, wm*64 + mf*16 + li, ks*4 + lg);
#pragma unroll
            for (int nf = 0; nf < 2; ++nf) b[nf] = fragRead(Bs, wn*32 + nf*16 + li, ks*4 + lg);
#pragma unroll
            for (int mf = 0; mf < 4; ++mf)
#pragma unroll
                for (int nf = 0; nf < 2; ++nf)
                    acc[mf][nf] = __builtin_amdgcn_mfma_f32_16x16x32_bf16(a[mf], b[nf], acc[mf][nf], 0, 0, 0);
        }
        __syncthreads();
    }
#pragma unroll
    for (int mf = 0; mf < 4; ++mf)
#pragma unroll
        for (int nf = 0; nf < 2; ++nf)
#pragma unroll
            for (int i = 0; i < 4; ++i) {
                const int row = m0 + wm*64 + mf*16 + lg*4 + i;
                const int col = n0 + wn*32 + nf*16 + li;
                out[(size_t)row*DMV + col] = acc[mf][nf][i];
            }
}

extern "C" void kernel_launch(void* const* d_in, const int* in_sizes, int n_in,
                              void* d_out, int out_size, void* d_ws, size_t ws_size,
                              hipStream_t stream)
{
    const float* x      = (const float*)d_in[0];
    const float* W_in   = (const float*)d_in[1];
    const float* conv_w = (const float*)d_in[2];
    const float* conv_b = (const float*)d_in[3];
    const float* ln_g   = (const float*)d_in[11];
    const float* ln_b   = (const float*)d_in[12];
    const float* W_out  = (const float*)d_in[13];
    float* out = (float*)d_out;

    float* Wc = (float*)d_ws;
    unsigned short* xf = (unsigned short*)((char*)d_ws + 192*192*sizeof(float));
    unsigned short* xc = xf + (size_t)MTOT * DIV;

    wc_kernel    <<<dim3(192),          192, 0, stream>>>(W_out, W_in, Wc);
    gemm_in_mfma <<<dim3(MTOT/128, 3),  256, 0, stream>>>(x, W_in, xf);
    dwconv_kernel<<<dim3(72, 6, B0V),   256, 0, stream>>>(xf, conv_w, conv_b, xc);
    boxln_kernel <<<dim3(MTOT/4),       256, 0, stream>>>(xc, ln_g, ln_b, xf);
    gemm_out_mfma<<<dim3(MTOT/128, 3),  256, 0, stream>>>(xf, W_out, x, Wc, out);
}

// Round 6
// 226.694 us; speedup vs baseline: 4.7740x; 1.0866x over previous
//
#include <hip/hip_runtime.h>
#include <cstddef>

#define B0V 8
#define HSV 96
#define WSV 96
#define DMV 192
#define DIV 384
#define MTOT (B0V*HSV*WSV)   // 73728

typedef __attribute__((ext_vector_type(8))) unsigned short ushort8v;
typedef __attribute__((ext_vector_type(8))) short short8v;
typedef __attribute__((ext_vector_type(4))) float f32x4;
typedef _Float16 h2 __attribute__((ext_vector_type(2)));
typedef _Float16 h8 __attribute__((ext_vector_type(8)));

__device__ __forceinline__ float bf2f(unsigned short u) {
    unsigned int i = ((unsigned int)u) << 16;
    float f; __builtin_memcpy(&f, &i, 4); return f;
}
__device__ __forceinline__ unsigned short f2bf(float f) {
    unsigned int i; __builtin_memcpy(&i, &f, 4);
    i += 0x7FFFu + ((i >> 16) & 1);
    return (unsigned short)(i >> 16);
}

// ---- LDS staging helpers: tile stored [ROWS][64] bf16, 16B chunks XOR-swizzled by (row&7) ----
template<int ROWS>
__device__ __forceinline__ void stageF32(const float* __restrict__ src, int ld,
                                         unsigned short* lds, int t) {
#pragma unroll
    for (int i = 0; i < ROWS*8/256; ++i) {
        const int cid = t + i*256;
        const int r = cid >> 3, cb = cid & 7;
        const float* p = src + (size_t)r*ld + cb*8;
        float4 f0 = *(const float4*)p;
        float4 f1 = *(const float4*)(p+4);
        ushort8v sv;
        sv[0]=f2bf(f0.x); sv[1]=f2bf(f0.y); sv[2]=f2bf(f0.z); sv[3]=f2bf(f0.w);
        sv[4]=f2bf(f1.x); sv[5]=f2bf(f1.y); sv[6]=f2bf(f1.z); sv[7]=f2bf(f1.w);
        *(ushort8v*)((char*)lds + r*128 + ((cb ^ (r&7))<<4)) = sv;
    }
}
template<int ROWS>
__device__ __forceinline__ void stageBF16(const unsigned short* __restrict__ src, int ld,
                                          unsigned short* lds, int t) {
#pragma unroll
    for (int i = 0; i < ROWS*8/256; ++i) {
        const int cid = t + i*256;
        const int r = cid >> 3, cb = cid & 7;
        ushort8v sv = *(const ushort8v*)(src + (size_t)r*ld + cb*8);
        *(ushort8v*)((char*)lds + r*128 + ((cb ^ (r&7))<<4)) = sv;
    }
}
__device__ __forceinline__ short8v fragRead(const unsigned short* lds, int row, int kchunk) {
    return *(const short8v*)((const char*)lds + row*128 + ((kchunk ^ (row&7))<<4));
}

// ---------------- K0a: Wc(192x192) = W_out(192x384) @ W_in_z(384x192) ----------------
__global__ __launch_bounds__(192) void wc_kernel(
    const float* __restrict__ Wout, const float* __restrict__ Win, float* __restrict__ Wc)
{
    const int o = blockIdx.x;
    const int c = threadIdx.x;
    __shared__ float wrow[384];
    for (int j = threadIdx.x; j < 384; j += 192) wrow[j] = Wout[(size_t)o*384 + j];
    __syncthreads();
    float acc = 0.f;
#pragma unroll 4
    for (int j = 0; j < 384; ++j)
        acc += wrow[j] * Win[(size_t)(384 + j)*192 + c];
    Wc[(size_t)o*192 + c] = acc;
}

// ---------------- K0b: pack conv weights f32[384][49] -> h2[49][192] ----------------
__global__ __launch_bounds__(256) void wprep_kernel(
    const float* __restrict__ cw, h2* __restrict__ w2h)
{
    const int idx = blockIdx.x*256 + threadIdx.x;
    if (idx < 49*192) {
        const int tap = idx / 192, cp = idx % 192;
        h2 v;
        v[0] = (_Float16)cw[(size_t)(2*cp  )*49 + tap];
        v[1] = (_Float16)cw[(size_t)(2*cp+1)*49 + tap];
        w2h[idx] = v;
    }
}

// ---------------- K1: xf(f16, Mx384) = x(Mx192) @ W_in_f^T  (MFMA) ----------------
__global__ __launch_bounds__(256) void gemm_in_mfma(
    const float* __restrict__ x, const float* __restrict__ W,
    _Float16* __restrict__ xf)
{
    __shared__ unsigned short As[128*64];
    __shared__ unsigned short Bs[128*64];
    const int t = threadIdx.x;
    const int m0 = blockIdx.x * 128, n0 = blockIdx.y * 128;
    const int wid = t >> 6, lane = t & 63;
    const int wm = wid >> 1, wn = wid & 1;
    const int li = lane & 15, lg = lane >> 4;

    f32x4 acc[4][4];
#pragma unroll
    for (int i = 0; i < 4; ++i)
#pragma unroll
        for (int j = 0; j < 4; ++j) acc[i][j] = (f32x4){0.f,0.f,0.f,0.f};

    for (int kb = 0; kb < 3; ++kb) {
        stageF32<128>(x + (size_t)m0*DMV + kb*64, DMV, As, t);
        stageF32<128>(W + (size_t)n0*DMV + kb*64, DMV, Bs, t);
        __syncthreads();
#pragma unroll
        for (int ks = 0; ks < 2; ++ks) {
            short8v a[4], b[4];
#pragma unroll
            for (int mf = 0; mf < 4; ++mf) a[mf] = fragRead(As, wm*64 + mf*16 + li, ks*4 + lg);
#pragma unroll
            for (int nf = 0; nf < 4; ++nf) b[nf] = fragRead(Bs, wn*64 + nf*16 + li, ks*4 + lg);
#pragma unroll
            for (int mf = 0; mf < 4; ++mf)
#pragma unroll
                for (int nf = 0; nf < 4; ++nf)
                    acc[mf][nf] = __builtin_amdgcn_mfma_f32_16x16x32_bf16(a[mf], b[nf], acc[mf][nf], 0, 0, 0);
        }
        __syncthreads();
    }
#pragma unroll
    for (int mf = 0; mf < 4; ++mf)
#pragma unroll
        for (int nf = 0; nf < 4; ++nf)
#pragma unroll
            for (int i = 0; i < 4; ++i) {
                const int row = m0 + wm*64 + mf*16 + lg*4 + i;
                const int col = n0 + wn*64 + nf*16 + li;
                xf[(size_t)row*DIV + col] = (_Float16)acc[mf][nf][i];
            }
}

// ---------------- K2: depthwise 7x7 conv — f16 LDS patch + packed half2 math ----------------
// tile 8h x 16w x 64c; 256 thr = 32 channel-pairs x 8 w-pairs; thread: 2ch x 2w x 8h
__global__ __launch_bounds__(256) void dwconv_kernel(
    const _Float16* __restrict__ xf, const h2* __restrict__ w2h,
    const float* __restrict__ cb, _Float16* __restrict__ xc)
{
    const int tile = blockIdx.x;            // 72 = 12h x 6w
    const int th = tile / 6, tw = tile % 6;
    const int h0 = th*8, w0 = tw*16;
    const int c0 = blockIdx.y*64, b = blockIdx.z;

    __shared__ _Float16 patch[14*22*64];    // 38.5 KB
    const int t = threadIdx.x;
    for (int idx = t; idx < 308*8; idx += 256) {
        const int sp = idx >> 3, c8 = idx & 7;
        const int ih = sp / 22, iw = sp % 22;
        const int gh = h0 - 3 + ih, gw = w0 - 3 + iw;
        ushort8v v;
#pragma unroll
        for (int j = 0; j < 8; ++j) v[j] = 0;
        if ((unsigned)gh < (unsigned)HSV && (unsigned)gw < (unsigned)WSV)
            v = *(const ushort8v*)(xf + (((size_t)b*HSV + gh)*WSV + gw)*DIV + c0 + c8*8);
        *(ushort8v*)(patch + sp*64 + c8*8) = v;
    }
    __syncthreads();

    const int cp = t & 31;          // channel pair within tile
    const int wq = t >> 5;          // w-pair index (0..7)

    h2 wreg[49];
    const h2* wp = w2h + (c0 >> 1) + cp;
#pragma unroll
    for (int k = 0; k < 49; ++k) wreg[k] = wp[k*192];

    h2 biasv;
    biasv[0] = (_Float16)cb[c0 + 2*cp];
    biasv[1] = (_Float16)cb[c0 + 2*cp + 1];
    h2 acc[8][2];
#pragma unroll
    for (int i = 0; i < 8; ++i) { acc[i][0] = biasv; acc[i][1] = biasv; }

    const h2* prow = (const h2*)patch;
#pragma unroll
    for (int ih = 0; ih < 14; ++ih) {
        h2 r[8];
#pragma unroll
        for (int j = 0; j < 8; ++j)
            r[j] = prow[(ih*22 + wq*2 + j)*32 + cp];
#pragma unroll
        for (int kh = 0; kh < 7; ++kh) {
            const int oh = ih - kh;
            if (oh >= 0 && oh < 8) {
#pragma unroll
                for (int kw = 0; kw < 7; ++kw) {
                    acc[oh][0] += wreg[kh*7 + kw] * r[kw];
                    acc[oh][1] += wreg[kh*7 + kw] * r[kw + 1];
                }
            }
        }
    }
    h2* xcp = (h2*)xc;
#pragma unroll
    for (int oh = 0; oh < 8; ++oh)
#pragma unroll
        for (int j = 0; j < 2; ++j)
            xcp[((((size_t)b*HSV + h0+oh)*WSV + (w0 + wq*2 + j))*DIV + c0)/2 + cp] = acc[oh][j];
}

// ---------------- K3: dilated 3x3 box-sum + LayerNorm — wave per pixel ----------------
__global__ __launch_bounds__(256) void boxln_kernel(
    const _Float16* __restrict__ xc,
    const float* __restrict__ g, const float* __restrict__ bta,
    unsigned short* __restrict__ yln)
{
    const int wid  = threadIdx.x >> 6;
    const int lane = threadIdx.x & 63;
    const int m = blockIdx.x * 4 + wid;
    const int b  = m / (HSV*WSV);
    const int hw = m % (HSV*WSV);
    const int h = hw / WSV, w = hw % WSV;

    const bool act = lane < 48;
    const int ch = lane * 8;
    const int dd = (ch >> 7) + 1;

    float s[8];
#pragma unroll
    for (int j = 0; j < 8; ++j) s[j] = 0.f;

#pragma unroll
    for (int a = -1; a <= 1; ++a)
#pragma unroll
        for (int bb = -1; bb <= 1; ++bb) {
            const int h2_ = h + a*dd, w2_ = w + bb*dd;
            if (act && (unsigned)h2_ < (unsigned)HSV && (unsigned)w2_ < (unsigned)WSV) {
                h8 v = *(const h8*)(xc + (((size_t)b*HSV + h2_)*WSV + w2_)*DIV + ch);
#pragma unroll
                for (int j = 0; j < 8; ++j) s[j] += (float)v[j];
            }
        }

    float ps = 0.f, ps2 = 0.f;
#pragma unroll
    for (int j = 0; j < 8; ++j) { ps += s[j]; ps2 += s[j]*s[j]; }
#pragma unroll
    for (int off = 32; off > 0; off >>= 1) {
        ps  += __shfl_xor(ps,  off);
        ps2 += __shfl_xor(ps2, off);
    }
    const float mu   = ps * (1.f/384.f);
    const float var  = ps2 * (1.f/384.f) - mu*mu;
    const float rstd = rsqrtf(var + 1e-5f);

    if (act) {
        float4 g0 = *(const float4*)(g + ch);
        float4 g1 = *(const float4*)(g + ch + 4);
        float4 b0 = *(const float4*)(bta + ch);
        float4 b1 = *(const float4*)(bta + ch + 4);
        float gv[8] = {g0.x,g0.y,g0.z,g0.w,g1.x,g1.y,g1.z,g1.w};
        float bv[8] = {b0.x,b0.y,b0.z,b0.w,b1.x,b1.y,b1.z,b1.w};
        ushort8v o;
#pragma unroll
        for (int j = 0; j < 8; ++j)
            o[j] = f2bf((s[j] - mu)*rstd*gv[j] + bv[j]);
        *(ushort8v*)(yln + (size_t)m*DIV + ch) = o;
    }
}

// ---------------- K4: out(f32, Mx192) = yln @ W_out^T + x @ Wc^T  (MFMA) ----------------
__global__ __launch_bounds__(256) void gemm_out_mfma(
    const unsigned short* __restrict__ Yl, const float* __restrict__ Wout,
    const float* __restrict__ x, const float* __restrict__ Wc,
    float* __restrict__ out)
{
    __shared__ unsigned short As[128*64];
    __shared__ unsigned short Bs[64*64];
    const int t = threadIdx.x;
    const int m0 = blockIdx.x * 128, n0 = blockIdx.y * 64;
    const int wid = t >> 6, lane = t & 63;
    const int wm = wid >> 1, wn = wid & 1;
    const int li = lane & 15, lg = lane >> 4;

    f32x4 acc[4][2];
#pragma unroll
    for (int i = 0; i < 4; ++i)
#pragma unroll
        for (int j = 0; j < 2; ++j) acc[i][j] = (f32x4){0.f,0.f,0.f,0.f};

    // phase 1: yln (bf16) @ W_out^T, K=384
    for (int kb = 0; kb < 6; ++kb) {
        stageBF16<128>(Yl + (size_t)m0*DIV + kb*64, DIV, As, t);
        stageF32<64> (Wout + (size_t)n0*DIV + kb*64, DIV, Bs, t);
        __syncthreads();
#pragma unroll
        for (int ks = 0; ks < 2; ++ks) {
            short8v a[4], b[2];
#pragma unroll
            for (int mf = 0; mf < 4; ++mf) a[mf] = fragRead(As, wm*64 + mf*16 + li, ks*4 + lg);
#pragma unroll
            for (int nf = 0; nf < 2; ++nf) b[nf] = fragRead(Bs, wn*32 + nf*16 + li, ks*4 + lg);
#pragma unroll
            for (int mf = 0; mf < 4; ++mf)
#pragma unroll
                for (int nf = 0; nf < 2; ++nf)
                    acc[mf][nf] = __builtin_amdgcn_mfma_f32_16x16x32_bf16(a[mf], b[nf], acc[mf][nf], 0, 0, 0);
        }
        __syncthreads();
    }
    // phase 2: x (f32->bf16) @ Wc^T, K=192
    for (int kb = 0; kb < 3; ++kb) {
        stageF32<128>(x  + (size_t)m0*DMV + kb*64, DMV, As, t);
        stageF32<64> (Wc + (size_t)n0*DMV + kb*64, DMV, Bs, t);
        __syncthreads();
#pragma unroll
        for (int ks = 0; ks < 2; ++ks) {
            short8v a[4], b[2];
#pragma unroll
            for (int mf = 0; mf < 4; ++mf) a[mf] = fragRead(As, wm*64 + mf*16 + li, ks*4 + lg);
#pragma unroll
            for (int nf = 0; nf < 2; ++nf) b[nf] = fragRead(Bs, wn*32 + nf*16 + li, ks*4 + lg);
#pragma unroll
            for (int mf = 0; mf < 4; ++mf)
#pragma unroll
                for (int nf = 0; nf < 2; ++nf)
                    acc[mf][nf] = __builtin_amdgcn_mfma_f32_16x16x32_bf16(a[mf], b[nf], acc[mf][nf], 0, 0, 0);
        }
        __syncthreads();
    }
#pragma unroll
    for (int mf = 0; mf < 4; ++mf)
#pragma unroll
        for (int nf = 0; nf < 2; ++nf)
#pragma unroll
            for (int i = 0; i < 4; ++i) {
                const int row = m0 + wm*64 + mf*16 + lg*4 + i;
                const int col = n0 + wn*32 + nf*16 + li;
                out[(size_t)row*DMV + col] = acc[mf][nf][i];
            }
}

extern "C" void kernel_launch(void* const* d_in, const int* in_sizes, int n_in,
                              void* d_out, int out_size, void* d_ws, size_t ws_size,
                              hipStream_t stream)
{
    const float* x      = (const float*)d_in[0];
    const float* W_in   = (const float*)d_in[1];
    const float* conv_w = (const float*)d_in[2];
    const float* conv_b = (const float*)d_in[3];
    const float* ln_g   = (const float*)d_in[11];
    const float* ln_b   = (const float*)d_in[12];
    const float* W_out  = (const float*)d_in[13];
    float* out = (float*)d_out;

    // ws: Wc f32[192*192] | w2h h2[49*192] | xf f16 M*384 (reused as bf16 yln) | xc f16 M*384
    float* Wc = (float*)d_ws;
    h2* w2h = (h2*)((char*)d_ws + 192*192*sizeof(float));
    _Float16* xf = (_Float16*)((char*)d_ws + 192*192*4 + 49*192*4);
    _Float16* xc = xf + (size_t)MTOT * DIV;

    wc_kernel    <<<dim3(192),          192, 0, stream>>>(W_out, W_in, Wc);
    wprep_kernel <<<dim3(37),           256, 0, stream>>>(conv_w, w2h);
    gemm_in_mfma <<<dim3(MTOT/128, 3),  256, 0, stream>>>(x, W_in, xf);
    dwconv_kernel<<<dim3(72, 6, B0V),   256, 0, stream>>>(xf, w2h, conv_b, xc);
    boxln_kernel <<<dim3(MTOT/4),       256, 0, stream>>>(xc, ln_g, ln_b,
                                                          (unsigned short*)xf);
    gemm_out_mfma<<<dim3(MTOT/128, 3),  256, 0, stream>>>((const unsigned short*)xf,
                                                          W_out, x, Wc, out);
}